// Round 9
// baseline (1505.921 us; speedup 1.0000x reference)
//
#include <hip/hip_runtime.h>
#include <hip/hip_fp16.h>

#define TT 512
#define BB 4096
#define PD 8        // prefetch depth = flag chunk size
#define NPROD 256   // producer blocks (16 rows each)
#define NCHUNK (TT / PD)

__device__ __forceinline__ const float* sel4(int g, const float* a, const float* b,
                                             const float* c, const float* d) {
    return g == 0 ? a : (g == 1 ? b : (g == 2 ? c : d));
}

__device__ __forceinline__ float sigmoid_fast(float x) {
    float e = __expf(-x);
    return __builtin_amdgcn_rcpf(1.0f + e);
}
__device__ __forceinline__ float tanh_fast(float x) {
    float e = __expf(-2.0f * x);
    return fmaf(2.0f, __builtin_amdgcn_rcpf(1.0f + e), -1.0f);
}

template<int CTRL>
__device__ __forceinline__ float dppf(float v) {
    int i = __builtin_amdgcn_mov_dpp(__float_as_int(v), CTRL, 0xf, 0xf, true);
    return __int_as_float(i);
}
#define QP(a,b,c,d) ((a) | ((b) << 2) | ((c) << 4) | ((d) << 6))
template<int CTRL>
__device__ __forceinline__ float quad_bcast(float v) { return dppf<CTRL>(v); }

__device__ __forceinline__ void waitflag(const unsigned* f) {
    while (__hip_atomic_load(f, __ATOMIC_ACQUIRE, __HIP_MEMORY_SCOPE_AGENT) == 0)
        __builtin_amdgcn_s_sleep(2);
}

// ================= FUSED: producer blocks (Ax) + consumer blocks (scan) =====================
// blocks 0..255: producer p, rows [p*16, p*16+16), all 512 t, flag per 8-t chunk.
// blocks 256..511: consumer cb = blk-256, rows [cb*16,+16), r8's proven scan16 + flag waits.
// Residency proof: 512 blocks x 4 waves = 2048 waves (chip cap 8192); <=8 blocks/CU (wave cap)
// x 8.5KB LDS = 68KB <= 160KB -> all blocks co-resident for ANY dispatch order; no deadlock.
__global__ __launch_bounds__(256) void qlstm_fused(
    const float* __restrict__ x,
    const float* __restrict__ Wf, const float* __restrict__ bf, const float* __restrict__ thf,
    const float* __restrict__ Wi, const float* __restrict__ bi, const float* __restrict__ thi,
    const float* __restrict__ Wu, const float* __restrict__ bu, const float* __restrict__ thu,
    const float* __restrict__ Wo, const float* __restrict__ bo, const float* __restrict__ tho,
    __half* __restrict__ Ax, unsigned* __restrict__ flags, float* __restrict__ out)
{
    int tid = threadIdx.x;
    __shared__ float xs[16][33][4];   // [row][j(+pad)][tt] ; b128 row-read, 2-way max conflict

    if (blockIdx.x < NPROD) {
        // ---------------- producer ----------------
        int p = blockIdx.x;
        int rbase = p * 16;
        int r  = tid >> 4;            // row within group (0..15)
        int oc = tid & 15;            // output column L = g*4+w (wire fastest: matches scan)
        int g  = oc >> 2, w = oc & 3;

        const float* Wg = sel4(g, Wf, Wi, Wu, Wo);
        float wreg[32];
#pragma unroll
        for (int j = 0; j < 32; ++j) wreg[j] = Wg[j * 4 + w];
        float bth = sel4(g, bf, bi, bu, bo)[w] + sel4(g, thf, thi, thu, tho)[w];

        for (int round = 0; round < 128; ++round) {
            int t0 = round * 4;
            // stage x[t0..t0+3][rbase..rbase+15][0..31] -> xs (transposed: tt innermost)
#pragma unroll
            for (int l = 0; l < 2; ++l) {
                int f = tid + (l << 8);
                int tt = f >> 7, inner = f & 127;
                const float4* src = (const float4*)(x + ((size_t)(t0 + tt) * BB + rbase) * 32);
                float4 v = src[inner];
                int row = inner >> 3, j0 = (inner & 7) * 4;
                xs[row][j0 + 0][tt] = v.x;
                xs[row][j0 + 1][tt] = v.y;
                xs[row][j0 + 2][tt] = v.z;
                xs[row][j0 + 3][tt] = v.w;
            }
            __syncthreads();

            float acc0 = bth, acc1 = bth, acc2 = bth, acc3 = bth;
#pragma unroll
            for (int j = 0; j < 32; ++j) {
                float4 xv = *(const float4*)&xs[r][j][0];
                float wj = wreg[j];
                acc0 = fmaf(xv.x, wj, acc0);
                acc1 = fmaf(xv.y, wj, acc1);
                acc2 = fmaf(xv.z, wj, acc2);
                acc3 = fmaf(xv.w, wj, acc3);
            }
            size_t obase = ((size_t)t0 * BB + rbase + r) * 16 + oc;
            Ax[obase]                    = __float2half(acc0);
            Ax[obase + (size_t)BB * 16]  = __float2half(acc1);
            Ax[obase + (size_t)BB * 32]  = __float2half(acc2);
            Ax[obase + (size_t)BB * 48]  = __float2half(acc3);
            __syncthreads();   // stores drained (vmcnt0 before barrier) + xs reusable

            if ((round & 1) && tid == 0)
                __hip_atomic_store(&flags[(size_t)p * NCHUNK + (round >> 1)], 1u,
                                   __ATOMIC_RELEASE, __HIP_MEMORY_SCOPE_AGENT);
        }
        return;
    }

    // ---------------- consumer: r8 scan16, plus per-chunk flag waits ----------------
    int cb  = blockIdx.x - NPROD;
    int gid = cb * 256 + tid;           // 0..65535
    int b   = gid >> 4;                 // batch row
    int L   = gid & 15;
    int w   = L & 3;                    // wire (quad lane)
    int g   = L >> 2;                   // gate: 0=f 1=i 2=u 3=o

    const float* Wg = sel4(g, Wf, Wi, Wu, Wo);
    float whA = Wg[(32 + w) * 4 + w];
    float whB = Wg[(32 + (w ^ 1)) * 4 + w];
    float whC = Wg[(32 + (w ^ 2)) * 4 + w];
    float whD = Wg[(32 + (w ^ 3)) * 4 + w];
    bool isU = (g == 2);
    bool wb0 = (w & 1) != 0, wb1 = (w & 2) != 0;

    float sH = isU ? 1.0f : 0.5f;
    float aA = isU ? 1.0f : 0.5f;
    float aB = isU ? 0.0f : 0.5f;

    float probe = (float)g;
    bool rorPlus = (dppf<0x124>(probe) == (float)((g + 1) & 3));

    const __half* Axp = Ax + (size_t)b * 16 + L;
    float* outp = out + (size_t)b * 4 + w;
    const unsigned* myflags = flags + (size_t)cb * NCHUNK;

    float hx = 0.f, cx = 0.f;
    __half buf[PD];
    waitflag(&myflags[0]);
#pragma unroll
    for (int k = 0; k < PD; ++k) buf[k] = Axp[(size_t)k * (BB * 16)];

    for (int tc = 0; tc < TT; tc += PD) {
        int c = tc >> 3;
        if (c + 1 < NCHUNK) waitflag(&myflags[c + 1]);
#pragma unroll
        for (int k = 0; k < PD; ++k) {
            int t = tc + k;
            float ax = __half2float(buf[k]);
            int tn = (t + PD < TT) ? t + PD : TT - 1;
            buf[k] = Axp[(size_t)tn * (BB * 16)];

            float h1 = dppf<QP(1, 0, 3, 2)>(hx);
            float h2 = dppf<QP(2, 3, 0, 1)>(hx);
            float h3 = dppf<QP(3, 2, 1, 0)>(hx);
            float t1 = fmaf(hx, whA, ax);
            t1 = fmaf(h1, whB, t1);
            float t2 = fmaf(h3, whD, h2 * whC);
            float C = __cosf(t1 + t2);

            float Cx1 = dppf<QP(1, 0, 3, 2)>(C);
            float P   = C * Cx1;
            float Px2 = dppf<QP(2, 3, 0, 1)>(P);
            float Q   = P * Px2;
            float m   = wb1 ? C : Cx1;
            float T   = Px2 * m;
            float z   = wb0 ? (wb1 ? Q : P) : T;

            float xA  = sH * z;
            float x2  = xA * xA;
            float num = xA * (x2 + 15.0f);
            float den = fmaf(x2, 6.0f, 15.0f);
            float act = fmaf(aA, num * __builtin_amdgcn_rcpf(den), aB);

            float ra = dppf<0x124>(act);
            float rb = dppf<0x128>(act);
            float rc = dppf<0x12C>(act);
            float r1 = rorPlus ? ra : rc;
            float r3 = rorPlus ? rc : ra;
            float f = (g == 0) ? act : (g == 1) ? r3 : (g == 2) ? rb : r1;
            float i = (g == 0) ? r1 : (g == 1) ? act : (g == 2) ? r3 : rb;
            float u = (g == 0) ? rb : (g == 1) ? r1 : (g == 2) ? act : r3;
            float o = (g == 0) ? r3 : (g == 1) ? rb : (g == 2) ? r1 : act;

            float c2 = fmaf(f, cx, i * u);
            cx = c2;
            float q2 = c2 * c2;
            float q4 = q2 * q2;
            float dn = fmaf(q2, 420.0f, fmaf(q4, 15.0f, 945.0f));
            float nm = c2 * fmaf(q2, 105.0f, 945.0f + q4);
            hx = o * (nm * __builtin_amdgcn_rcpf(dn));

            outp[(size_t)t * 16384] = hx;
        }
    }
    outp[(size_t)TT * 16384] = hx;
    outp[(size_t)TT * 16384 + 16384] = cx;
}

// ================= mid path (ws >= Ax only): r8's two-kernel version =======================
__global__ __launch_bounds__(256) void qlstm_pre(
    const float* __restrict__ x,
    const float* __restrict__ Wf, const float* __restrict__ bf, const float* __restrict__ thf,
    const float* __restrict__ Wi, const float* __restrict__ bi, const float* __restrict__ thi,
    const float* __restrict__ Wu, const float* __restrict__ bu, const float* __restrict__ thu,
    const float* __restrict__ Wo, const float* __restrict__ bo, const float* __restrict__ tho,
    __half* __restrict__ Ax)
{
    __shared__ float4 Wl[32][4];
    __shared__ float4 bias4[4];
    __shared__ float xs[256 * 33];
    int tid = threadIdx.x;
    for (int idx = tid; idx < 512; idx += 256) {
        int j = idx >> 4, c = idx & 15, g = c >> 2, w = c & 3;
        ((float*)Wl)[idx] = sel4(g, Wf, Wi, Wu, Wo)[j * 4 + w];
    }
    if (tid < 16) {
        int g = tid >> 2, w = tid & 3;
        ((float*)bias4)[tid] = sel4(g, bf, bi, bu, bo)[w] + sel4(g, thf, thi, thu, tho)[w];
    }

    size_t rbase = (size_t)blockIdx.x * 256;
    const float4* xg = (const float4*)(x + rbase * 32);
#pragma unroll
    for (int it = 0; it < 8; ++it) {
        int i = it * 256 + tid;
        float4 v = xg[i];
        int r = i >> 3, c = (i & 7) * 4;
        float* p = &xs[r * 33 + c];
        p[0] = v.x; p[1] = v.y; p[2] = v.z; p[3] = v.w;
    }
    __syncthreads();

    float4 acc[4];
#pragma unroll
    for (int q = 0; q < 4; ++q) acc[q] = bias4[q];

    const float* xr = &xs[tid * 33];
#pragma unroll
    for (int j = 0; j < 32; ++j) {
        float xj = xr[j];
#pragma unroll
        for (int q = 0; q < 4; ++q) {
            float4 wv = Wl[j][q];
            acc[q].x = fmaf(xj, wv.x, acc[q].x);
            acc[q].y = fmaf(xj, wv.y, acc[q].y);
            acc[q].z = fmaf(xj, wv.z, acc[q].z);
            acc[q].w = fmaf(xj, wv.w, acc[q].w);
        }
    }

    union { __half2 h2; unsigned u; } cv;
    uint4 s0, s1;
    cv.h2 = __floats2half2_rn(acc[0].x, acc[0].y); s0.x = cv.u;
    cv.h2 = __floats2half2_rn(acc[0].z, acc[0].w); s0.y = cv.u;
    cv.h2 = __floats2half2_rn(acc[1].x, acc[1].y); s0.z = cv.u;
    cv.h2 = __floats2half2_rn(acc[1].z, acc[1].w); s0.w = cv.u;
    cv.h2 = __floats2half2_rn(acc[2].x, acc[2].y); s1.x = cv.u;
    cv.h2 = __floats2half2_rn(acc[2].z, acc[2].w); s1.y = cv.u;
    cv.h2 = __floats2half2_rn(acc[3].x, acc[3].y); s1.z = cv.u;
    cv.h2 = __floats2half2_rn(acc[3].z, acc[3].w); s1.w = cv.u;
    uint4* Ap = (uint4*)Ax + (rbase + tid) * 2;
    Ap[0] = s0; Ap[1] = s1;
}

__global__ __launch_bounds__(256) void qlstm_scan16(
    const __half* __restrict__ Ax,
    const float* __restrict__ Wf, const float* __restrict__ Wi,
    const float* __restrict__ Wu, const float* __restrict__ Wo,
    float* __restrict__ out)
{
    int tid = threadIdx.x;
    int gid = blockIdx.x * 256 + tid;
    int b   = gid >> 4;
    int L   = gid & 15;
    int w   = L & 3;
    int g   = L >> 2;

    const float* Wg = sel4(g, Wf, Wi, Wu, Wo);
    float whA = Wg[(32 + w) * 4 + w];
    float whB = Wg[(32 + (w ^ 1)) * 4 + w];
    float whC = Wg[(32 + (w ^ 2)) * 4 + w];
    float whD = Wg[(32 + (w ^ 3)) * 4 + w];
    bool isU = (g == 2);
    bool wb0 = (w & 1) != 0, wb1 = (w & 2) != 0;

    float sH = isU ? 1.0f : 0.5f;
    float aA = isU ? 1.0f : 0.5f;
    float aB = isU ? 0.0f : 0.5f;

    float probe = (float)g;
    bool rorPlus = (dppf<0x124>(probe) == (float)((g + 1) & 3));

    const __half* Axp = Ax + (size_t)b * 16 + L;
    float* outp = out + (size_t)b * 4 + w;

    float hx = 0.f, cx = 0.f;
    __half buf[PD];
#pragma unroll
    for (int k = 0; k < PD; ++k) buf[k] = Axp[(size_t)k * (BB * 16)];

    for (int tc = 0; tc < TT; tc += PD) {
#pragma unroll
        for (int k = 0; k < PD; ++k) {
            int t = tc + k;
            float ax = __half2float(buf[k]);
            int tn = (t + PD < TT) ? t + PD : TT - 1;
            buf[k] = Axp[(size_t)tn * (BB * 16)];

            float h1 = dppf<QP(1, 0, 3, 2)>(hx);
            float h2 = dppf<QP(2, 3, 0, 1)>(hx);
            float h3 = dppf<QP(3, 2, 1, 0)>(hx);
            float t1 = fmaf(hx, whA, ax);
            t1 = fmaf(h1, whB, t1);
            float t2 = fmaf(h3, whD, h2 * whC);
            float C = __cosf(t1 + t2);

            float Cx1 = dppf<QP(1, 0, 3, 2)>(C);
            float P   = C * Cx1;
            float Px2 = dppf<QP(2, 3, 0, 1)>(P);
            float Q   = P * Px2;
            float m   = wb1 ? C : Cx1;
            float T   = Px2 * m;
            float z   = wb0 ? (wb1 ? Q : P) : T;

            float xA  = sH * z;
            float x2  = xA * xA;
            float num = xA * (x2 + 15.0f);
            float den = fmaf(x2, 6.0f, 15.0f);
            float act = fmaf(aA, num * __builtin_amdgcn_rcpf(den), aB);

            float ra = dppf<0x124>(act);
            float rb = dppf<0x128>(act);
            float rc = dppf<0x12C>(act);
            float r1 = rorPlus ? ra : rc;
            float r3 = rorPlus ? rc : ra;
            float f = (g == 0) ? act : (g == 1) ? r3 : (g == 2) ? rb : r1;
            float i = (g == 0) ? r1 : (g == 1) ? act : (g == 2) ? r3 : rb;
            float u = (g == 0) ? rb : (g == 1) ? r1 : (g == 2) ? act : r3;
            float o = (g == 0) ? r3 : (g == 1) ? rb : (g == 2) ? r1 : act;

            float c2 = fmaf(f, cx, i * u);
            cx = c2;
            float q2 = c2 * c2;
            float q4 = q2 * q2;
            float dn = fmaf(q2, 420.0f, fmaf(q4, 15.0f, 945.0f));
            float nm = c2 * fmaf(q2, 105.0f, 945.0f + q4);
            hx = o * (nm * __builtin_amdgcn_rcpf(dn));

            outp[(size_t)t * 16384] = hx;
        }
    }
    outp[(size_t)TT * 16384] = hx;
    outp[(size_t)TT * 16384 + 16384] = cx;
}

// ================= fallback (no workspace) =================================================
__global__ __launch_bounds__(64, 1) void qlstm_scan_fb(
    const float* __restrict__ x,
    const float* __restrict__ Wf, const float* __restrict__ bf, const float* __restrict__ thf,
    const float* __restrict__ Wi, const float* __restrict__ bi, const float* __restrict__ thi,
    const float* __restrict__ Wu, const float* __restrict__ bu, const float* __restrict__ thu,
    const float* __restrict__ Wo, const float* __restrict__ bo, const float* __restrict__ tho,
    float* __restrict__ out)
{
    int lane = threadIdx.x;
    int gid  = blockIdx.x * 64 + lane;
    int b    = gid >> 2;
    int g    = lane & 3;

    const float* Wg = sel4(g, Wf, Wi, Wu, Wo);
    float wh[4][4];
#pragma unroll
    for (int j = 0; j < 4; ++j)
#pragma unroll
        for (int w = 0; w < 4; ++w)
            wh[j][w] = Wg[(32 + j) * 4 + w];

    __shared__ float4 Wl[32][4];
    float bias[4];
    for (int idx = lane; idx < 512; idx += 64) {
        int j = idx >> 4, c = idx & 15, gg = c >> 2, w = c & 3;
        ((float*)Wl)[idx] = sel4(gg, Wf, Wi, Wu, Wo)[j * 4 + w];
    }
#pragma unroll
    for (int w = 0; w < 4; ++w)
        bias[w] = sel4(g, bf, bi, bu, bo)[w] + sel4(g, thf, thi, thu, tho)[w];
    __syncthreads();

    float hx[4] = {0, 0, 0, 0}, cx[4] = {0, 0, 0, 0};
    const float4* xp = (const float4*)x + (size_t)b * 8;

    for (int t = 0; t < TT; ++t) {
        float4 xc[8];
#pragma unroll
        for (int k = 0; k < 8; ++k) xc[k] = xp[(size_t)t * (BB * 8) + k];
        float ax[4];
#pragma unroll
        for (int w = 0; w < 4; ++w) ax[w] = bias[w];
#pragma unroll
        for (int j = 0; j < 32; ++j) {
            float xj = ((const float*)xc)[j];
            float4 wv = Wl[j][g];
            ax[0] = fmaf(xj, wv.x, ax[0]);
            ax[1] = fmaf(xj, wv.y, ax[1]);
            ax[2] = fmaf(xj, wv.z, ax[2]);
            ax[3] = fmaf(xj, wv.w, ax[3]);
        }
        float C[4];
#pragma unroll
        for (int w = 0; w < 4; ++w) {
            float a0 = fmaf(hx[0], wh[0][w], ax[w]);
            float a1 = fmaf(hx[2], wh[2][w], hx[1] * wh[1][w]);
            a0 = fmaf(hx[3], wh[3][w], a0);
            C[w] = __cosf(a0 + a1);
        }
        float t12 = C[1] * C[2];
        float z[4];
        z[1] = C[0] * C[1];
        z[2] = C[0] * t12;
        z[0] = t12 * C[3];
        z[3] = z[2] * C[3];
        bool isU = (g == 2);
        float act[4];
#pragma unroll
        for (int w = 0; w < 4; ++w) {
            float zz = isU ? z[w] + z[w] : z[w];
            float y = sigmoid_fast(zz);
            act[w] = isU ? fmaf(2.0f, y, -1.0f) : y;
        }
#pragma unroll
        for (int w = 0; w < 4; ++w) {
            float fw = quad_bcast<QP(0, 0, 0, 0)>(act[w]);
            float iw = quad_bcast<QP(1, 1, 1, 1)>(act[w]);
            float uw = quad_bcast<QP(2, 2, 2, 2)>(act[w]);
            float ow = quad_bcast<QP(3, 3, 3, 3)>(act[w]);
            float c2 = fmaf(fw, cx[w], iw * uw);
            cx[w] = c2;
            hx[w] = ow * tanh_fast(c2);
        }
        float o01 = (g & 1) ? hx[1] : hx[0];
        float o23 = (g & 1) ? hx[3] : hx[2];
        out[(size_t)t * 16384 + gid] = (g & 2) ? o23 : o01;
    }
    float o01 = (g & 1) ? hx[1] : hx[0];
    float o23 = (g & 1) ? hx[3] : hx[2];
    out[(size_t)TT * 16384 + gid] = (g & 2) ? o23 : o01;
    float c01 = (g & 1) ? cx[1] : cx[0];
    float c23 = (g & 1) ? cx[3] : cx[2];
    out[(size_t)TT * 16384 + 16384 + gid] = (g & 2) ? c23 : c01;
}

extern "C" void kernel_launch(void* const* d_in, const int* in_sizes, int n_in,
                              void* d_out, int out_size, void* d_ws, size_t ws_size,
                              hipStream_t stream) {
    const float* x   = (const float*)d_in[0];
    const float* Wf  = (const float*)d_in[1];
    const float* bf  = (const float*)d_in[2];
    const float* thf = (const float*)d_in[3];
    const float* Wi  = (const float*)d_in[4];
    const float* bi  = (const float*)d_in[5];
    const float* thi = (const float*)d_in[6];
    const float* Wu  = (const float*)d_in[7];
    const float* bu  = (const float*)d_in[8];
    const float* thu = (const float*)d_in[9];
    const float* Wo  = (const float*)d_in[10];
    const float* bo  = (const float*)d_in[11];
    const float* tho = (const float*)d_in[12];
    float* out = (float*)d_out;

    size_t axBytes   = (size_t)TT * BB * 16 * sizeof(__half);        // 64 MB
    size_t flagBytes = (size_t)NPROD * NCHUNK * sizeof(unsigned);    // 64 KB

    if (ws_size >= axBytes + flagBytes) {
        __half* Ax = (__half*)d_ws;
        unsigned* flags = (unsigned*)((char*)d_ws + axBytes);
        hipMemsetAsync(flags, 0, flagBytes, stream);
        qlstm_fused<<<2 * NPROD, 256, 0, stream>>>(
            x, Wf, bf, thf, Wi, bi, thi, Wu, bu, thu, Wo, bo, tho, Ax, flags, out);
    } else if (ws_size >= axBytes) {
        __half* Ax = (__half*)d_ws;
        qlstm_pre<<<(TT * BB) / 256, 256, 0, stream>>>(
            x, Wf, bf, thf, Wi, bi, thi, Wu, bu, thu, Wo, bo, tho, Ax);
        qlstm_scan16<<<(BB * 16) / 256, 256, 0, stream>>>(Ax, Wf, Wi, Wu, Wo, out);
    } else {
        qlstm_scan_fb<<<(BB * 4) / 64, 64, 0, stream>>>(
            x, Wf, bf, thf, Wi, bi, thi, Wu, bu, thu, Wo, bo, tho, out);
    }
}

// Round 10
// 134.154 us; speedup vs baseline: 11.2253x; 11.2253x over previous
//
#include <hip/hip_runtime.h>
#include <hip/hip_fp16.h>

#define TT 512
#define BB 4096
#define PD 16   // prefetch distance & store-batch chunk; TT % PD == 0

__device__ __forceinline__ const float* sel4(int g, const float* a, const float* b,
                                             const float* c, const float* d) {
    return g == 0 ? a : (g == 1 ? b : (g == 2 ? c : d));
}

__device__ __forceinline__ float sigmoid_fast(float x) {
    float e = __expf(-x);
    return __builtin_amdgcn_rcpf(1.0f + e);
}
__device__ __forceinline__ float tanh_fast(float x) {
    float e = __expf(-2.0f * x);
    return fmaf(2.0f, __builtin_amdgcn_rcpf(1.0f + e), -1.0f);
}

// DPP move: quad_perm 0x00-0xFF, row_ror 0x120+N (row = 16 lanes)
template<int CTRL>
__device__ __forceinline__ float dppf(float v) {
    int i = __builtin_amdgcn_mov_dpp(__float_as_int(v), CTRL, 0xf, 0xf, true);
    return __int_as_float(i);
}
#define QP(a,b,c,d) ((a) | ((b) << 2) | ((c) << 4) | ((d) << 6))
template<int CTRL>
__device__ __forceinline__ float quad_bcast(float v) { return dppf<CTRL>(v); }

// ---------------- Phase 1: Ax[t*B+b][16] = x @ Wx + (b + theta), stored fp16 ----------------
__global__ __launch_bounds__(256) void qlstm_pre(
    const float* __restrict__ x,
    const float* __restrict__ Wf, const float* __restrict__ bf, const float* __restrict__ thf,
    const float* __restrict__ Wi, const float* __restrict__ bi, const float* __restrict__ thi,
    const float* __restrict__ Wu, const float* __restrict__ bu, const float* __restrict__ thu,
    const float* __restrict__ Wo, const float* __restrict__ bo, const float* __restrict__ tho,
    __half* __restrict__ Ax)
{
    __shared__ float4 Wl[32][4];
    __shared__ float4 bias4[4];
    __shared__ float xs[256 * 33];
    int tid = threadIdx.x;
    for (int idx = tid; idx < 512; idx += 256) {
        int j = idx >> 4, c = idx & 15, g = c >> 2, w = c & 3;
        ((float*)Wl)[idx] = sel4(g, Wf, Wi, Wu, Wo)[j * 4 + w];
    }
    if (tid < 16) {
        int g = tid >> 2, w = tid & 3;
        ((float*)bias4)[tid] = sel4(g, bf, bi, bu, bo)[w] + sel4(g, thf, thi, thu, tho)[w];
    }

    size_t rbase = (size_t)blockIdx.x * 256;
    const float4* xg = (const float4*)(x + rbase * 32);
#pragma unroll
    for (int it = 0; it < 8; ++it) {
        int i = it * 256 + tid;
        float4 v = xg[i];
        int r = i >> 3, c = (i & 7) * 4;
        float* p = &xs[r * 33 + c];
        p[0] = v.x; p[1] = v.y; p[2] = v.z; p[3] = v.w;
    }
    __syncthreads();

    float4 acc[4];
#pragma unroll
    for (int q = 0; q < 4; ++q) acc[q] = bias4[q];

    const float* xr = &xs[tid * 33];
#pragma unroll
    for (int j = 0; j < 32; ++j) {
        float xj = xr[j];
#pragma unroll
        for (int q = 0; q < 4; ++q) {
            float4 wv = Wl[j][q];
            acc[q].x = fmaf(xj, wv.x, acc[q].x);
            acc[q].y = fmaf(xj, wv.y, acc[q].y);
            acc[q].z = fmaf(xj, wv.z, acc[q].z);
            acc[q].w = fmaf(xj, wv.w, acc[q].w);
        }
    }

    union { __half2 h2; unsigned u; } cv;
    uint4 s0, s1;
    cv.h2 = __floats2half2_rn(acc[0].x, acc[0].y); s0.x = cv.u;
    cv.h2 = __floats2half2_rn(acc[0].z, acc[0].w); s0.y = cv.u;
    cv.h2 = __floats2half2_rn(acc[1].x, acc[1].y); s0.z = cv.u;
    cv.h2 = __floats2half2_rn(acc[1].z, acc[1].w); s0.w = cv.u;
    cv.h2 = __floats2half2_rn(acc[2].x, acc[2].y); s1.x = cv.u;
    cv.h2 = __floats2half2_rn(acc[2].z, acc[2].w); s1.y = cv.u;
    cv.h2 = __floats2half2_rn(acc[3].x, acc[3].y); s1.z = cv.u;
    cv.h2 = __floats2half2_rn(acc[3].z, acc[3].w); s1.w = cv.u;
    uint4* Ap = (uint4*)Ax + (rbase + tid) * 2;
    Ap[0] = s0; Ap[1] = s1;
}

// ---------------- Phase 2: scan, 16 lanes per batch row (lane = gate*4 + wire) --------------
// r8 structure & step math; vmem discipline changed: (1) only L<4 lanes store (dedup 4x,
// 64B-contiguous per wave), (2) stores batched per 16-step chunk from hxs[] regs,
// (3) 16-deep prefetch. Goal: no per-step waitcnt covering store retirement.
__global__ __launch_bounds__(256) void qlstm_scan16(
    const __half* __restrict__ Ax,
    const float* __restrict__ Wf, const float* __restrict__ Wi,
    const float* __restrict__ Wu, const float* __restrict__ Wo,
    float* __restrict__ out)
{
    int tid = threadIdx.x;
    int gid = blockIdx.x * 256 + tid;   // 0..65535
    int b   = gid >> 4;                 // batch row
    int L   = gid & 15;
    int w   = L & 3;                    // wire (quad lane)
    int g   = L >> 2;                   // gate: 0=f 1=i 2=u 3=o

    const float* Wg = sel4(g, Wf, Wi, Wu, Wo);
    float whA = Wg[(32 + w) * 4 + w];
    float whB = Wg[(32 + (w ^ 1)) * 4 + w];
    float whC = Wg[(32 + (w ^ 2)) * 4 + w];
    float whD = Wg[(32 + (w ^ 3)) * 4 + w];
    bool isU = (g == 2);
    bool wb0 = (w & 1) != 0, wb1 = (w & 2) != 0;

    float sH = isU ? 1.0f : 0.5f;
    float aA = isU ? 1.0f : 0.5f;
    float aB = isU ? 0.0f : 0.5f;

    float probe = (float)g;
    bool rorPlus = (dppf<0x124>(probe) == (float)((g + 1) & 3));

    const __half* Axp = Ax + (size_t)b * 16 + L;
    float* outp4 = out + (size_t)b * 4 + L;   // used only by L<4 lanes (g=0, w=L)

    float hx = 0.f, cx = 0.f;
    __half buf[PD];
#pragma unroll
    for (int k = 0; k < PD; ++k) buf[k] = Axp[(size_t)k * (BB * 16)];

#define SCAN_STEP(t, PREFETCH)                                                  \
    do {                                                                        \
        float ax = __half2float(buf[k]);                                        \
        if (PREFETCH) buf[k] = Axp[(size_t)((t) + PD) * (BB * 16)];             \
        float h1 = dppf<QP(1, 0, 3, 2)>(hx);                                    \
        float h2 = dppf<QP(2, 3, 0, 1)>(hx);                                    \
        float h3 = dppf<QP(3, 2, 1, 0)>(hx);                                    \
        float t1 = fmaf(hx, whA, ax);                                           \
        t1 = fmaf(h1, whB, t1);                                                 \
        float t2 = fmaf(h3, whD, h2 * whC);                                     \
        float C = __cosf(t1 + t2);                                              \
        float Cx1 = dppf<QP(1, 0, 3, 2)>(C);                                    \
        float P   = C * Cx1;                                                    \
        float Px2 = dppf<QP(2, 3, 0, 1)>(P);                                    \
        float Q   = P * Px2;                                                    \
        float m   = wb1 ? C : Cx1;                                              \
        float T   = Px2 * m;                                                    \
        float z   = wb0 ? (wb1 ? Q : P) : T;                                    \
        float xA  = sH * z;                                                     \
        float x2  = xA * xA;                                                    \
        float num = xA * (x2 + 15.0f);                                          \
        float den = fmaf(x2, 6.0f, 15.0f);                                      \
        float act = fmaf(aA, num * __builtin_amdgcn_rcpf(den), aB);             \
        float ra = dppf<0x124>(act);                                            \
        float rb = dppf<0x128>(act);                                            \
        float rc = dppf<0x12C>(act);                                            \
        float r1 = rorPlus ? ra : rc;                                           \
        float r3 = rorPlus ? rc : ra;                                           \
        float f = (g == 0) ? act : (g == 1) ? r3 : (g == 2) ? rb : r1;          \
        float i = (g == 0) ? r1 : (g == 1) ? act : (g == 2) ? r3 : rb;          \
        float u = (g == 0) ? rb : (g == 1) ? r1 : (g == 2) ? act : r3;          \
        float o = (g == 0) ? r3 : (g == 1) ? rb : (g == 2) ? r1 : act;          \
        float c2 = fmaf(f, cx, i * u);                                          \
        cx = c2;                                                                \
        float q2 = c2 * c2;                                                     \
        float q4 = q2 * q2;                                                     \
        float dn = fmaf(q2, 420.0f, fmaf(q4, 15.0f, 945.0f));                   \
        float nm = c2 * fmaf(q2, 105.0f, 945.0f + q4);                          \
        hx = o * (nm * __builtin_amdgcn_rcpf(dn));                              \
        hxs[k] = hx;                                                            \
    } while (0)

    for (int tc = 0; tc < TT - PD; tc += PD) {   // main chunks: unconditional prefetch
        float hxs[PD];
#pragma unroll
        for (int k = 0; k < PD; ++k) { int t = tc + k; SCAN_STEP(t, 1); }
        if (L < 4) {                              // dedup: g=0 quad holds w=0..3
#pragma unroll
            for (int k = 0; k < PD; ++k)
                outp4[(size_t)(tc + k) * 16384] = hxs[k];
        }
    }
    {
        float hxs[PD];
#pragma unroll
        for (int k = 0; k < PD; ++k) { int t = TT - PD + k; SCAN_STEP(t, 0); }
        if (L < 4) {
#pragma unroll
            for (int k = 0; k < PD; ++k)
                outp4[(size_t)(TT - PD + k) * 16384] = hxs[k];
        }
    }
    if (L < 4) {
        outp4[(size_t)TT * 16384] = hx;
        outp4[(size_t)TT * 16384 + 16384] = cx;
    }
#undef SCAN_STEP
}

// ---------------- Fallback (no workspace): 4 lanes/row, recompute x@W per step --------------
__global__ __launch_bounds__(64, 1) void qlstm_scan_fb(
    const float* __restrict__ x,
    const float* __restrict__ Wf, const float* __restrict__ bf, const float* __restrict__ thf,
    const float* __restrict__ Wi, const float* __restrict__ bi, const float* __restrict__ thi,
    const float* __restrict__ Wu, const float* __restrict__ bu, const float* __restrict__ thu,
    const float* __restrict__ Wo, const float* __restrict__ bo, const float* __restrict__ tho,
    float* __restrict__ out)
{
    int lane = threadIdx.x;
    int gid  = blockIdx.x * 64 + lane;
    int b    = gid >> 2;
    int g    = lane & 3;

    const float* Wg = sel4(g, Wf, Wi, Wu, Wo);
    float wh[4][4];
#pragma unroll
    for (int j = 0; j < 4; ++j)
#pragma unroll
        for (int w = 0; w < 4; ++w)
            wh[j][w] = Wg[(32 + j) * 4 + w];

    __shared__ float4 Wl[32][4];
    float bias[4];
    for (int idx = lane; idx < 512; idx += 64) {
        int j = idx >> 4, c = idx & 15, gg = c >> 2, w = c & 3;
        ((float*)Wl)[idx] = sel4(gg, Wf, Wi, Wu, Wo)[j * 4 + w];
    }
#pragma unroll
    for (int w = 0; w < 4; ++w)
        bias[w] = sel4(g, bf, bi, bu, bo)[w] + sel4(g, thf, thi, thu, tho)[w];
    __syncthreads();

    float hx[4] = {0, 0, 0, 0}, cx[4] = {0, 0, 0, 0};
    const float4* xp = (const float4*)x + (size_t)b * 8;

    for (int t = 0; t < TT; ++t) {
        float4 xc[8];
#pragma unroll
        for (int k = 0; k < 8; ++k) xc[k] = xp[(size_t)t * (BB * 8) + k];
        float ax[4];
#pragma unroll
        for (int w = 0; w < 4; ++w) ax[w] = bias[w];
#pragma unroll
        for (int j = 0; j < 32; ++j) {
            float xj = ((const float*)xc)[j];
            float4 wv = Wl[j][g];
            ax[0] = fmaf(xj, wv.x, ax[0]);
            ax[1] = fmaf(xj, wv.y, ax[1]);
            ax[2] = fmaf(xj, wv.z, ax[2]);
            ax[3] = fmaf(xj, wv.w, ax[3]);
        }
        float C[4];
#pragma unroll
        for (int w = 0; w < 4; ++w) {
            float a0 = fmaf(hx[0], wh[0][w], ax[w]);
            float a1 = fmaf(hx[2], wh[2][w], hx[1] * wh[1][w]);
            a0 = fmaf(hx[3], wh[3][w], a0);
            C[w] = __cosf(a0 + a1);
        }
        float t12 = C[1] * C[2];
        float z[4];
        z[1] = C[0] * C[1];
        z[2] = C[0] * t12;
        z[0] = t12 * C[3];
        z[3] = z[2] * C[3];
        bool isU = (g == 2);
        float act[4];
#pragma unroll
        for (int w = 0; w < 4; ++w) {
            float zz = isU ? z[w] + z[w] : z[w];
            float y = sigmoid_fast(zz);
            act[w] = isU ? fmaf(2.0f, y, -1.0f) : y;
        }
#pragma unroll
        for (int w = 0; w < 4; ++w) {
            float fw = quad_bcast<QP(0, 0, 0, 0)>(act[w]);
            float iw = quad_bcast<QP(1, 1, 1, 1)>(act[w]);
            float uw = quad_bcast<QP(2, 2, 2, 2)>(act[w]);
            float ow = quad_bcast<QP(3, 3, 3, 3)>(act[w]);
            float c2 = fmaf(fw, cx[w], iw * uw);
            cx[w] = c2;
            hx[w] = ow * tanh_fast(c2);
        }
        float o01 = (g & 1) ? hx[1] : hx[0];
        float o23 = (g & 1) ? hx[3] : hx[2];
        out[(size_t)t * 16384 + gid] = (g & 2) ? o23 : o01;
    }
    float o01 = (g & 1) ? hx[1] : hx[0];
    float o23 = (g & 1) ? hx[3] : hx[2];
    out[(size_t)TT * 16384 + gid] = (g & 2) ? o23 : o01;
    float c01 = (g & 1) ? cx[1] : cx[0];
    float c23 = (g & 1) ? cx[3] : cx[2];
    out[(size_t)TT * 16384 + 16384 + gid] = (g & 2) ? c23 : c01;
}

extern "C" void kernel_launch(void* const* d_in, const int* in_sizes, int n_in,
                              void* d_out, int out_size, void* d_ws, size_t ws_size,
                              hipStream_t stream) {
    const float* x   = (const float*)d_in[0];
    const float* Wf  = (const float*)d_in[1];
    const float* bf  = (const float*)d_in[2];
    const float* thf = (const float*)d_in[3];
    const float* Wi  = (const float*)d_in[4];
    const float* bi  = (const float*)d_in[5];
    const float* thi = (const float*)d_in[6];
    const float* Wu  = (const float*)d_in[7];
    const float* bu  = (const float*)d_in[8];
    const float* thu = (const float*)d_in[9];
    const float* Wo  = (const float*)d_in[10];
    const float* bo  = (const float*)d_in[11];
    const float* tho = (const float*)d_in[12];
    float* out = (float*)d_out;

    size_t need = (size_t)TT * BB * 16 * sizeof(__half);   // 64 MB
    if (ws_size >= need) {
        __half* Ax = (__half*)d_ws;
        qlstm_pre<<<(TT * BB) / 256, 256, 0, stream>>>(
            x, Wf, bf, thf, Wi, bi, thi, Wu, bu, thu, Wo, bo, tho, Ax);
        qlstm_scan16<<<(BB * 16) / 256, 256, 0, stream>>>(Ax, Wf, Wi, Wu, Wo, out);
    } else {
        qlstm_scan_fb<<<(BB * 4) / 64, 64, 0, stream>>>(
            x, Wf, bf, thf, Wi, bi, thi, Wu, bu, thu, Wo, bo, tho, out);
    }
}